// Round 1
// baseline (341.577 us; speedup 1.0000x reference)
//
#include <hip/hip_runtime.h>
#include <math.h>

namespace {
constexpr int B_ = 16;
constexpr int L_ = 1534;
constexpr int C_ = 16;
constexpr int LC = L_ * C_;        // 24544
constexpr int O1 = 1023;           // L - 512 + 1
constexpr int O2 = 512;
constexpr int K_ = 8192;           // SIZE * C
constexpr int KH = 4096;           // K half
constexpr int OUTL = 1535;         // L + 1
constexpr float EPS = 1e-3f;
constexpr int H1P_FLOATS = 2 * B_ * O1;  // 32736 floats of ws for k-half partials
}

// ---------------- Stage 1: h1 partials ----------------
// h1[b,o] = dot(x[b*LC + o*16 .. +8192], W1[o*8192 .. +8192])   (bias/ELU in stage 2)
// Block: (jb, khalf). Covers o = jb*4..+3, k in [khalf*4096, +4096).
// 512 threads = 4 batch-groups (4 batches each) x 128 k-lanes.
// Thread reads x4 at absolute window offset m once, reuses across 4 j's with
// shifted W rows (w index kk = m_rel - 16*jj). Register tile: acc[4 j][4 b].
template<bool GUARD>
__device__ __forceinline__ void h1_step(const float* __restrict__ x,
                                        const float* __restrict__ W1,
                                        int o0, int k0, int bg, int m4,
                                        float (&acc)[4][4]) {
  const int m_rel = m4 * 4;          // float offset in window [k0, k0+4144)
  const int m_abs = o0 * 16 + m_rel; // float offset in x row
  float4 xv[4];
  bool xok = true;
  if (GUARD) xok = (m4 < (k0 >> 2) + 1036) && (m_abs <= LC - 4);
#pragma unroll
  for (int bi = 0; bi < 4; ++bi) {
    xv[bi] = xok ? *(const float4*)(x + (bg * 4 + bi) * LC + m_abs)
                 : make_float4(0.f, 0.f, 0.f, 0.f);
  }
#pragma unroll
  for (int jj = 0; jj < 4; ++jj) {
    const int o = o0 + jj;
    const int kk = m_rel - 16 * jj;
    bool wok = true;
    if (GUARD) wok = (o < O1) && (kk >= k0) && (kk <= k0 + KH - 4);
    const float4 wv = wok ? *(const float4*)(W1 + o * K_ + kk)
                          : make_float4(0.f, 0.f, 0.f, 0.f);
#pragma unroll
    for (int bi = 0; bi < 4; ++bi) {
      acc[jj][bi] = fmaf(xv[bi].x, wv.x, acc[jj][bi]);
      acc[jj][bi] = fmaf(xv[bi].y, wv.y, acc[jj][bi]);
      acc[jj][bi] = fmaf(xv[bi].z, wv.z, acc[jj][bi]);
      acc[jj][bi] = fmaf(xv[bi].w, wv.w, acc[jj][bi]);
    }
  }
}

__global__ __launch_bounds__(512, 4) void k_h1(const float* __restrict__ x,
                                               const float* __restrict__ W1,
                                               float* __restrict__ h1p,
                                               float* __restrict__ gacc) {
  const int bid = blockIdx.x;
  const int h = bid & 1;
  const int o0 = (bid >> 1) * 4;
  const int k0 = h * KH;
  const int t = (int)threadIdx.x;
  const int bg = t >> 7;   // 0..3 -> batches bg*4..+3
  const int kl = t & 127;  // k-lane
  const int m4base = (k0 >> 2) + kl;

  float acc[4][4];
#pragma unroll
  for (int j = 0; j < 4; ++j)
#pragma unroll
    for (int i = 0; i < 4; ++i) acc[j][i] = 0.f;

  if (o0 + 4 <= O1) {  // all blocks except the last jb: steps 1..7 need no guards
    h1_step<true>(x, W1, o0, k0, bg, m4base, acc);
#pragma unroll
    for (int s = 1; s <= 7; ++s)
      h1_step<false>(x, W1, o0, k0, bg, m4base + s * 128, acc);
    h1_step<true>(x, W1, o0, k0, bg, m4base + 8 * 128, acc);
  } else {
    for (int s = 0; s <= 8; ++s)
      h1_step<true>(x, W1, o0, k0, bg, m4base + s * 128, acc);
  }

  // butterfly reduce each acc over the 64-lane wave
#pragma unroll
  for (int j = 0; j < 4; ++j)
#pragma unroll
    for (int i = 0; i < 4; ++i) {
      float v = acc[j][i];
#pragma unroll
      for (int off = 32; off >= 1; off >>= 1) v += __shfl_xor(v, off, 64);
      acc[j][i] = v;
    }

  __shared__ float red[8][16];
  const int wave = t >> 6;
  const int lane = t & 63;
  if (lane == 0) {
#pragma unroll
    for (int j = 0; j < 4; ++j)
#pragma unroll
      for (int i = 0; i < 4; ++i) red[wave][j * 4 + i] = acc[j][i];
  }
  __syncthreads();
  if (t < 64) {
    const int bg2 = t >> 4, jj = (t >> 2) & 3, bi = t & 3;
    const float v = red[bg2 * 2][jj * 4 + bi] + red[bg2 * 2 + 1][jj * 4 + bi];
    const int o = o0 + jj;
    if (o < O1) h1p[(h * B_ + bg2 * 4 + bi) * O1 + o] = v;
  }
  // zero the lin/sig accumulators for stage 2 (stream order guarantees visibility)
  if (bid == 0 && t < 32) gacc[t] = 0.f;
}

// ---------------- Stage 2: h2 -> partial lin/sig ----------------
// grid = 16 b x 8 o2-tiles (64 o2 each), 256 threads = 4 waves.
// Wave handles one o2 at a time: lanes cover s, coalesced W2 reads, shfl reduce.
// lin/sig are linear in h2 -> atomically accumulate per-block partials.
__global__ __launch_bounds__(256) void k_h2(const float* __restrict__ h1p,
                                            const float* __restrict__ b1,
                                            const float* __restrict__ W2,
                                            const float* __restrict__ b2,
                                            const float* __restrict__ Wl,
                                            const float* __restrict__ Wsg,
                                            float* __restrict__ gacc) {
  const int bid = blockIdx.x;
  const int b = bid >> 3;
  const int tile = bid & 7;
  const int base = tile * 64;
  const int t = (int)threadIdx.x;
  const int wave = t >> 6;
  const int lane = t & 63;

  __shared__ float hw[575];  // h1 window [base, base+575)
  for (int i = t; i < 575; i += 256) {
    const int o = base + i;
    const float v = h1p[b * O1 + o] + h1p[(B_ + b) * O1 + o] + b1[o];
    hw[i] = v > 0.f ? v : expm1f(v);  // ELU, alpha=1
  }
  __syncthreads();

  float lin_acc = 0.f, sig_acc = 0.f;
  for (int i = wave; i < 64; i += 4) {
    const int o2 = base + i;
    const float4 wa = *(const float4*)(W2 + o2 * 512 + lane * 4);
    const float4 wb = *(const float4*)(W2 + o2 * 512 + 256 + lane * 4);
    const int sa = i + lane * 4;
    float a = 0.f;
    a = fmaf(hw[sa + 0], wa.x, a);
    a = fmaf(hw[sa + 1], wa.y, a);
    a = fmaf(hw[sa + 2], wa.z, a);
    a = fmaf(hw[sa + 3], wa.w, a);
    a = fmaf(hw[sa + 256], wb.x, a);
    a = fmaf(hw[sa + 257], wb.y, a);
    a = fmaf(hw[sa + 258], wb.z, a);
    a = fmaf(hw[sa + 259], wb.w, a);
#pragma unroll
    for (int off = 32; off >= 1; off >>= 1) a += __shfl_xor(a, off, 64);
    const float h2 = a + b2[o2];  // all lanes hold the full sum
    lin_acc = fmaf(h2, Wl[o2], lin_acc);
    sig_acc = fmaf(h2, Wsg[o2], sig_acc);
  }

  __shared__ float lred[4], sred[4];
  if (lane == 0) { lred[wave] = lin_acc; sred[wave] = sig_acc; }
  __syncthreads();
  if (t == 0) {
    atomicAdd(&gacc[b], lred[0] + lred[1] + lred[2] + lred[3]);
    atomicAdd(&gacc[16 + b], sred[0] + sred[1] + sred[2] + sred[3]);
  }
}

// ---------------- Stage 3: residual + batchnorm epilogue ----------------
__global__ __launch_bounds__(256) void k_out(const float* __restrict__ x,
                                             const float* __restrict__ gacc,
                                             const float* __restrict__ bl,
                                             const float* __restrict__ bs,
                                             const float* __restrict__ gamma,
                                             const float* __restrict__ beta,
                                             const float* __restrict__ mmean,
                                             const float* __restrict__ mvar,
                                             float* __restrict__ out) {
  const int f4 = blockIdx.x * 256 + (int)threadIdx.x;
  if (f4 >= B_ * OUTL * 4) return;  // 98240 float4s
  const int b = f4 / (OUTL * 4);
  const int q = f4 - b * (OUTL * 4);
  const int l = q >> 2;
  const int c0 = (q & 3) * 4;

  const float lin = gacc[b] + bl[0];
  const float sv = gacc[16 + b] + bs[0];
  const float g = lin * (1.f / (1.f + expf(-sv)));

  float4 xin = make_float4(0.f, 0.f, 0.f, 0.f);
  if (l < L_) xin = *(const float4*)(x + b * LC + l * 16 + c0);

  const float4 gm = *(const float4*)(gamma + c0);
  const float4 bt = *(const float4*)(beta + c0);
  const float4 mm = *(const float4*)(mmean + c0);
  const float4 mv = *(const float4*)(mvar + c0);

  float4 r;
  r.x = (xin.x + g - mm.x) * (rsqrtf(mv.x + EPS) * gm.x) + bt.x;
  r.y = (xin.y + g - mm.y) * (rsqrtf(mv.y + EPS) * gm.y) + bt.y;
  r.z = (xin.z + g - mm.z) * (rsqrtf(mv.z + EPS) * gm.z) + bt.z;
  r.w = (xin.w + g - mm.w) * (rsqrtf(mv.w + EPS) * gm.w) + bt.w;
  *(float4*)(out + f4 * 4) = r;
}

extern "C" void kernel_launch(void* const* d_in, const int* in_sizes, int n_in,
                              void* d_out, int out_size, void* d_ws, size_t ws_size,
                              hipStream_t stream) {
  const float* x    = (const float*)d_in[0];
  const float* W1   = (const float*)d_in[1];
  const float* b1   = (const float*)d_in[2];
  const float* W2   = (const float*)d_in[3];
  const float* b2   = (const float*)d_in[4];
  const float* Wl   = (const float*)d_in[5];
  const float* bl   = (const float*)d_in[6];
  const float* Wsg  = (const float*)d_in[7];
  const float* bs   = (const float*)d_in[8];
  const float* gm   = (const float*)d_in[9];
  const float* bt   = (const float*)d_in[10];
  const float* mmn  = (const float*)d_in[11];
  const float* mvr  = (const float*)d_in[12];

  float* ws   = (float*)d_ws;
  float* h1p  = ws;                // [2][16][1023] k-half partials
  float* gacc = ws + H1P_FLOATS;   // lin[16], sig[16]

  k_h1<<<512, 512, 0, stream>>>(x, W1, h1p, gacc);
  k_h2<<<128, 256, 0, stream>>>(h1p, b1, W2, b2, Wl, Wsg, gacc);
  k_out<<<(B_ * OUTL * 4 + 255) / 256, 256, 0, stream>>>(
      x, gacc, bl, bs, gm, bt, mmn, mvr, (float*)d_out);
}

// Round 2
// 126.881 us; speedup vs baseline: 2.6921x; 2.6921x over previous
//
#include <hip/hip_runtime.h>
#include <math.h>

namespace {
constexpr int B_ = 16;
constexpr int L_ = 1534;
constexpr int LC = L_ * 16;        // 24544 floats per batch row
constexpr int O1 = 1023;           // L - 512 + 1
constexpr int K_ = 8192;           // SIZE * C
constexpr int KSPLIT = 8;
constexpr int KQ = K_ / KSPLIT;    // 1024
constexpr int KC = 256;            // chunk (floats of K per inner stage)
constexpr int OUTL = 1535;         // L + 1
constexpr float EPS = 1e-3f;
constexpr int XS_F4 = 112;         // x LDS row: 448 floats (192 max shift + 256)
constexpr int WS_F4 = 80;          // W LDS row: 320 floats (48 halo + 256 + pad)
constexpr int H1P_FLOATS = KSPLIT * B_ * O1;  // 130944
}

// ---------------- Stage 1: h1 k-split partials ----------------
// h1[b,o] = sum_q x[b, o*16+q] * W1[o, q].
// Block (tile, split): o in [tile*16, +16), q in [split*1024, +1024).
// 512 threads = bgrp(2) x ogrp(4) x ks(64). Thread tile: 4 o x 8 b, acc[32].
// Per KC=256 chunk: stage W rows (with 48-float low-side halo, zero-filled
// outside [0,K)) and x window into LDS; thread anchors x at float4 index
// (ogrp*16 + ks) and reads W at shifted index (ks - 4*jj + 12). Each (o,q)
// is computed exactly once device-wide (halo chaining across chunks/splits;
// split 7 runs a 5th chunk for the tail).
__global__ __launch_bounds__(512, 4) void k_h1(const float* __restrict__ x,
                                               const float* __restrict__ W1,
                                               float* __restrict__ h1p,
                                               float* __restrict__ gacc) {
  __shared__ float4 xs[16 * XS_F4];    // 28 KB
  __shared__ float4 wsld[16 * WS_F4];  // 20 KB

  const int tile = (int)blockIdx.x >> 3;  // 0..63
  const int split = (int)blockIdx.x & 7;  // 0..7
  const int o0 = tile * 16;
  const int q0 = split * KQ;
  const int t = (int)threadIdx.x;
  const int bgrp = t >> 8;        // 0..1
  const int ogrp = (t >> 6) & 3;  // 0..3
  const int ks = t & 63;          // 0..63

  float acc[4][8];
#pragma unroll
  for (int j = 0; j < 4; ++j)
#pragma unroll
    for (int i = 0; i < 8; ++i) acc[j][i] = 0.f;

  const int nc = (split == KSPLIT - 1) ? 5 : 4;  // split 7 covers the K tail
  for (int c = 0; c < nc; ++c) {
    const int qc = q0 + c * KC;  // absolute W-column base of this chunk

    // stage W: wsld[ol*80 + f4] covers q = qc - 48 + f4*4; zero outside [0,K)
#pragma unroll
    for (int i = 0; i < 3; ++i) {
      const int idx = t + i * 512;
      if (idx < 16 * WS_F4) {
        const int ol = idx / WS_F4;
        const int f4 = idx - ol * WS_F4;
        const int q = qc - 48 + f4 * 4;
        const int o = o0 + ol;
        float4 v = make_float4(0.f, 0.f, 0.f, 0.f);
        if (o < O1 && q >= 0 && q <= K_ - 4)
          v = *(const float4*)(W1 + o * K_ + q);
        wsld[idx] = v;
      }
    }
    // stage x: xs[b*112 + f4] covers p = o0*16 + qc + f4*4; zero past end
#pragma unroll
    for (int i = 0; i < 4; ++i) {
      const int idx = t + i * 512;
      if (idx < 16 * XS_F4) {
        const int b = idx / XS_F4;
        const int f4 = idx - b * XS_F4;
        const int p = o0 * 16 + qc + f4 * 4;
        float4 v = make_float4(0.f, 0.f, 0.f, 0.f);
        if (p <= LC - 4) v = *(const float4*)(x + b * LC + p);
        xs[idx] = v;
      }
    }
    __syncthreads();

    float4 wv[4];
#pragma unroll
    for (int jj = 0; jj < 4; ++jj)
      wv[jj] = wsld[(ogrp * 4 + jj) * WS_F4 + (ks - 4 * jj + 12)];
    float4 xv[8];
#pragma unroll
    for (int bi = 0; bi < 8; ++bi)
      xv[bi] = xs[(bgrp * 8 + bi) * XS_F4 + (ogrp * 16 + ks)];
#pragma unroll
    for (int jj = 0; jj < 4; ++jj)
#pragma unroll
      for (int bi = 0; bi < 8; ++bi) {
        acc[jj][bi] = fmaf(xv[bi].x, wv[jj].x, acc[jj][bi]);
        acc[jj][bi] = fmaf(xv[bi].y, wv[jj].y, acc[jj][bi]);
        acc[jj][bi] = fmaf(xv[bi].z, wv[jj].z, acc[jj][bi]);
        acc[jj][bi] = fmaf(xv[bi].w, wv[jj].w, acc[jj][bi]);
      }
    __syncthreads();
  }

  // ---- reduce over ks (64 partials per output), 4 rounds of jj, LDS reuse
  float* redf = (float*)xs;
  float4* red4 = xs;
  const int cls = bgrp * 4 + ogrp;  // 0..7
#pragma unroll
  for (int r = 0; r < 4; ++r) {
    __syncthreads();
    red4[(cls * 64 + ks) * 2 + 0] =
        make_float4(acc[r][0], acc[r][1], acc[r][2], acc[r][3]);
    red4[(cls * 64 + ks) * 2 + 1] =
        make_float4(acc[r][4], acc[r][5], acc[r][6], acc[r][7]);
    __syncthreads();
    const int out = t >> 3;   // 0..63: rcls(8) x bi(8)
    const int seg = t & 7;
    const int rcls = out >> 3, bi = out & 7;
    float v = 0.f;
#pragma unroll
    for (int j = 0; j < 8; ++j)
      v += redf[(rcls * 64 + seg * 8 + j) * 8 + bi];
    v += __shfl_xor(v, 1, 64);
    v += __shfl_xor(v, 2, 64);
    v += __shfl_xor(v, 4, 64);
    if (seg == 0) {
      const int b = (rcls >> 2) * 8 + bi;
      const int o = o0 + (rcls & 3) * 4 + r;
      if (o < O1) h1p[(split * B_ + b) * O1 + o] = v;
    }
  }
  // zero lin/sig accumulators for stage 2 (stream order guarantees visibility)
  if (blockIdx.x == 0 && t < 32) gacc[t] = 0.f;
}

// ---------------- Stage 2: h2 -> partial lin/sig ----------------
__global__ __launch_bounds__(256) void k_h2(const float* __restrict__ h1p,
                                            const float* __restrict__ b1,
                                            const float* __restrict__ W2,
                                            const float* __restrict__ b2,
                                            const float* __restrict__ Wl,
                                            const float* __restrict__ Wsg,
                                            float* __restrict__ gacc) {
  const int bid = (int)blockIdx.x;
  const int b = bid >> 3;
  const int tile = bid & 7;
  const int base = tile * 64;
  const int t = (int)threadIdx.x;
  const int wave = t >> 6;
  const int lane = t & 63;

  __shared__ float hw[575];  // ELU(h1) window [base, base+575)
  for (int i = t; i < 575; i += 256) {
    const int o = base + i;
    float v = b1[o];
#pragma unroll
    for (int s = 0; s < KSPLIT; ++s) v += h1p[(s * B_ + b) * O1 + o];
    hw[i] = v > 0.f ? v : expm1f(v);  // ELU alpha=1
  }
  __syncthreads();

  float lin_acc = 0.f, sig_acc = 0.f;
  for (int i = wave; i < 64; i += 4) {
    const int o2 = base + i;
    const float4 wa = *(const float4*)(W2 + o2 * 512 + lane * 4);
    const float4 wb = *(const float4*)(W2 + o2 * 512 + 256 + lane * 4);
    const int sa = i + lane * 4;
    float a = 0.f;
    a = fmaf(hw[sa + 0], wa.x, a);
    a = fmaf(hw[sa + 1], wa.y, a);
    a = fmaf(hw[sa + 2], wa.z, a);
    a = fmaf(hw[sa + 3], wa.w, a);
    a = fmaf(hw[sa + 256], wb.x, a);
    a = fmaf(hw[sa + 257], wb.y, a);
    a = fmaf(hw[sa + 258], wb.z, a);
    a = fmaf(hw[sa + 259], wb.w, a);
#pragma unroll
    for (int off = 32; off >= 1; off >>= 1) a += __shfl_xor(a, off, 64);
    const float h2 = a + b2[o2];
    lin_acc = fmaf(h2, Wl[o2], lin_acc);
    sig_acc = fmaf(h2, Wsg[o2], sig_acc);
  }

  __shared__ float lred[4], sred[4];
  if (lane == 0) { lred[wave] = lin_acc; sred[wave] = sig_acc; }
  __syncthreads();
  if (t == 0) {
    atomicAdd(&gacc[b], lred[0] + lred[1] + lred[2] + lred[3]);
    atomicAdd(&gacc[16 + b], sred[0] + sred[1] + sred[2] + sred[3]);
  }
}

// ---------------- Stage 3: residual + batchnorm epilogue ----------------
__global__ __launch_bounds__(256) void k_out(const float* __restrict__ x,
                                             const float* __restrict__ gacc,
                                             const float* __restrict__ bl,
                                             const float* __restrict__ bs,
                                             const float* __restrict__ gamma,
                                             const float* __restrict__ beta,
                                             const float* __restrict__ mmean,
                                             const float* __restrict__ mvar,
                                             float* __restrict__ out) {
  const int f4 = blockIdx.x * 256 + (int)threadIdx.x;
  if (f4 >= B_ * OUTL * 4) return;
  const int b = f4 / (OUTL * 4);
  const int q = f4 - b * (OUTL * 4);
  const int l = q >> 2;
  const int c0 = (q & 3) * 4;

  const float lin = gacc[b] + bl[0];
  const float sv = gacc[16 + b] + bs[0];
  const float g = lin * (1.f / (1.f + expf(-sv)));

  float4 xin = make_float4(0.f, 0.f, 0.f, 0.f);
  if (l < L_) xin = *(const float4*)(x + b * LC + l * 16 + c0);

  const float4 gm = *(const float4*)(gamma + c0);
  const float4 bt = *(const float4*)(beta + c0);
  const float4 mm = *(const float4*)(mmean + c0);
  const float4 mv = *(const float4*)(mvar + c0);

  float4 r;
  r.x = (xin.x + g - mm.x) * (rsqrtf(mv.x + EPS) * gm.x) + bt.x;
  r.y = (xin.y + g - mm.y) * (rsqrtf(mv.y + EPS) * gm.y) + bt.y;
  r.z = (xin.z + g - mm.z) * (rsqrtf(mv.z + EPS) * gm.z) + bt.z;
  r.w = (xin.w + g - mm.w) * (rsqrtf(mv.w + EPS) * gm.w) + bt.w;
  *(float4*)(out + f4 * 4) = r;
}

extern "C" void kernel_launch(void* const* d_in, const int* in_sizes, int n_in,
                              void* d_out, int out_size, void* d_ws, size_t ws_size,
                              hipStream_t stream) {
  const float* x    = (const float*)d_in[0];
  const float* W1   = (const float*)d_in[1];
  const float* b1   = (const float*)d_in[2];
  const float* W2   = (const float*)d_in[3];
  const float* b2   = (const float*)d_in[4];
  const float* Wl   = (const float*)d_in[5];
  const float* bl   = (const float*)d_in[6];
  const float* Wsg  = (const float*)d_in[7];
  const float* bs   = (const float*)d_in[8];
  const float* gm   = (const float*)d_in[9];
  const float* bt   = (const float*)d_in[10];
  const float* mmn  = (const float*)d_in[11];
  const float* mvr  = (const float*)d_in[12];

  float* ws   = (float*)d_ws;
  float* h1p  = ws;                // [8][16][1023] k-split partials
  float* gacc = ws + H1P_FLOATS;   // lin[16], sig[16]

  k_h1<<<512, 512, 0, stream>>>(x, W1, h1p, gacc);
  k_h2<<<128, 256, 0, stream>>>(h1p, b1, W2, b2, Wl, Wsg, gacc);
  k_out<<<(B_ * OUTL * 4 + 255) / 256, 256, 0, stream>>>(
      x, gacc, bl, bs, gm, bt, mmn, mvr, (float*)d_out);
}